// Round 1
// baseline (554.885 us; speedup 1.0000x reference)
//
#include <hip/hip_runtime.h>
#include <hip/hip_bf16.h>
#include <stdint.h>

#define S_LEN 2048
#define HIDDEN 3584
#define NH 28
#define NKH 4
#define DH 128
#define NG 7          // NH / NKH
#define NQKV 4608     // (NH + 2*NKH) * DH
#define QD 3584       // NH*DH
#define KD 512        // NKH*DH

using bf16x8 = __attribute__((ext_vector_type(8))) __bf16;
using f32x4  = __attribute__((ext_vector_type(4))) float;

#define AS3(p) ((__attribute__((address_space(3))) void*)(p))
#define AS1(p) ((const __attribute__((address_space(1))) void*)(p))

__device__ __forceinline__ unsigned short f2bf(float f) {
    unsigned u = __float_as_uint(f);
    u += 0x7FFFu + ((u >> 16) & 1u);
    return (unsigned short)(u >> 16);
}

// ---------------- f32 -> bf16 convert (vectorized) ----------------
__global__ void cvt_f32_bf16(const float* __restrict__ in,
                             unsigned short* __restrict__ out, int n4) {
    int i = blockIdx.x * blockDim.x + threadIdx.x;
    if (i >= n4) return;
    float4 v = ((const float4*)in)[i];
    ushort4 o;
    o.x = f2bf(v.x); o.y = f2bf(v.y); o.z = f2bf(v.z); o.w = f2bf(v.w);
    ((ushort4*)out)[i] = o;
}

// ---------------- bf16 GEMM: C[M][N] = A[M][K] * B[N][K]^T (+bias) ----------------
// 128x128 tile, BK=64, 256 threads (4 waves, each 64x64), global_load_lds staging
// with pre-swizzled global source (XOR (row&7)<<4 on 16B chunks) -> conflict-free ds_read_b128.
__global__ __launch_bounds__(256) void gemm_bf16(
    const unsigned short* __restrict__ A,
    const unsigned short* __restrict__ B,
    float* __restrict__ C,
    const float* __restrict__ bias,
    int M, int N, int K)
{
    __shared__ __align__(16) unsigned char smem[32768];
    unsigned char* As = smem;           // 128 rows x 128B (64 bf16), swizzled
    unsigned char* Bs = smem + 16384;

    const int tid  = threadIdx.x;
    const int lane = tid & 63;
    const int w    = tid >> 6;
    const int lr   = lane & 15;
    const int lg   = lane >> 4;
    const int m0   = blockIdx.y * 128;
    const int n0   = blockIdx.x * 128;
    const int wm   = (w >> 1) * 64;
    const int wn   = (w & 1) * 64;

    f32x4 acc[4][4] = {};

    // staging geometry: chunk c (0..15) covers rows c*8..c*8+7; lane -> (row, chunk-in-row)
    const int srow  = lane >> 3;                       // row within chunk
    const int scolb = 16 * ((lane & 7) ^ srow);        // pre-swizzled source col byte

    const int nk = K >> 6;
    for (int kt = 0; kt < nk; ++kt) {
        __syncthreads();
        const long kbyte = (long)kt * 128;
        #pragma unroll
        for (int i = 0; i < 4; ++i) {
            const int c   = w * 4 + i;
            const int row = c * 8 + srow;
            const unsigned char* srcA =
                (const unsigned char*)A + (long)(m0 + row) * (K * 2) + kbyte + scolb;
            __builtin_amdgcn_global_load_lds(AS1(srcA), AS3(As + c * 1024), 16, 0, 0);
            const unsigned char* srcB =
                (const unsigned char*)B + (long)(n0 + row) * (K * 2) + kbyte + scolb;
            __builtin_amdgcn_global_load_lds(AS1(srcB), AS3(Bs + c * 1024), 16, 0, 0);
        }
        __syncthreads();
        #pragma unroll
        for (int kk = 0; kk < 2; ++kk) {
            bf16x8 af[4], bfr[4];
            #pragma unroll
            for (int mi = 0; mi < 4; ++mi) {
                const int row  = wm + mi * 16 + lr;
                const int colb = kk * 64 + lg * 16;
                af[mi] = *(const bf16x8*)(As + row * 128 + (colb ^ ((row & 7) << 4)));
            }
            #pragma unroll
            for (int ni = 0; ni < 4; ++ni) {
                const int row  = wn + ni * 16 + lr;
                const int colb = kk * 64 + lg * 16;
                bfr[ni] = *(const bf16x8*)(Bs + row * 128 + (colb ^ ((row & 7) << 4)));
            }
            #pragma unroll
            for (int mi = 0; mi < 4; ++mi)
                #pragma unroll
                for (int ni = 0; ni < 4; ++ni)
                    acc[mi][ni] = __builtin_amdgcn_mfma_f32_16x16x32_bf16(
                        af[mi], bfr[ni], acc[mi][ni], 0, 0, 0);
        }
    }

    #pragma unroll
    for (int mi = 0; mi < 4; ++mi) {
        #pragma unroll
        for (int ni = 0; ni < 4; ++ni) {
            const int col = n0 + wn + ni * 16 + lr;
            const float bv = bias ? bias[col] : 0.0f;
            #pragma unroll
            for (int j = 0; j < 4; ++j) {
                const int rowg = m0 + wm + mi * 16 + lg * 4 + j;
                C[(long)rowg * N + col] = acc[mi][ni][j] + bv;
            }
        }
    }
}

// ---------------- QKV post: RMSNorm(q,k) + RoPE, layout shuffle ----------------
__global__ __launch_bounds__(256) void qkv_post(
    const float* __restrict__ qkv,       // [S][NQKV] (bias already added)
    const int* __restrict__ positions,
    const float* __restrict__ qnw,       // [QD]
    const float* __restrict__ knw,       // [KD]
    unsigned short* __restrict__ qb,     // [NH][S][DH]
    unsigned short* __restrict__ kb,     // [NKH][S][DH]
    unsigned short* __restrict__ vt)     // [NKH][DH][S]
{
    const int s   = blockIdx.x;
    const int tid = threadIdx.x;
    const float* rowp = qkv + (long)s * NQKV;
    __shared__ float red[256];
    __shared__ float s_rq, s_rk;

    float aq = 0.f;
    for (int i = tid; i < QD; i += 256) { float v = rowp[i]; aq += v * v; }
    red[tid] = aq; __syncthreads();
    for (int off = 128; off > 0; off >>= 1) {
        if (tid < off) red[tid] += red[tid + off];
        __syncthreads();
    }
    if (tid == 0) s_rq = rsqrtf(red[0] / (float)QD + 1e-6f);
    __syncthreads();

    float ak = 0.f;
    for (int i = tid; i < KD; i += 256) { float v = rowp[QD + i]; ak += v * v; }
    red[tid] = ak; __syncthreads();
    for (int off = 128; off > 0; off >>= 1) {
        if (tid < off) red[tid] += red[tid + off];
        __syncthreads();
    }
    if (tid == 0) s_rk = rsqrtf(red[0] / (float)KD + 1e-6f);
    __syncthreads();

    const float rq  = s_rq, rk = s_rk;
    const float pos = (float)positions[s];
    const float c_lnf = 0.21586735253866598f; // ln(1e6)/64

    for (int u = tid; u < NH * 64; u += 256) {
        const int h = u >> 6, j = u & 63;
        const float inv = expf(-(float)j * c_lnf);
        float sn, cs;
        sincosf(pos * inv, &sn, &cs);
        const float x1 = rowp[h * DH + j]      * rq * qnw[h * DH + j];
        const float x2 = rowp[h * DH + 64 + j] * rq * qnw[h * DH + 64 + j];
        qb[((long)h * S_LEN + s) * DH + j]      = f2bf(x1 * cs - x2 * sn);
        qb[((long)h * S_LEN + s) * DH + 64 + j] = f2bf(x2 * cs + x1 * sn);
    }
    for (int u = tid; u < NKH * 64; u += 256) {
        const int h = u >> 6, j = u & 63;
        const float inv = expf(-(float)j * c_lnf);
        float sn, cs;
        sincosf(pos * inv, &sn, &cs);
        const float x1 = rowp[QD + h * DH + j]      * rk * knw[h * DH + j];
        const float x2 = rowp[QD + h * DH + 64 + j] * rk * knw[h * DH + 64 + j];
        kb[((long)h * S_LEN + s) * DH + j]      = f2bf(x1 * cs - x2 * sn);
        kb[((long)h * S_LEN + s) * DH + 64 + j] = f2bf(x2 * cs + x1 * sn);
    }
    for (int u = tid; u < KD; u += 256) {
        const int h = u >> 7, d = u & 127;
        vt[((long)h * DH + d) * S_LEN + s] = f2bf(rowp[QD + KD + u]);
    }
}

// ---------------- flash attention: 1 wave / (head, 16-q-row tile) ----------------
__global__ __launch_bounds__(64) void attn_fwd(
    const unsigned short* __restrict__ qb,   // [NH][S][DH]
    const unsigned short* __restrict__ kb,   // [NKH][S][DH]
    const unsigned short* __restrict__ vt,   // [NKH][DH][S]
    unsigned short* __restrict__ attnb)      // [S][QD]
{
    const int q0   = blockIdx.x * 16;
    const int h    = blockIdx.y;
    const int kh   = h / NG;
    const int lane = threadIdx.x;
    const int lr   = lane & 15;
    const int lg   = lane >> 4;

    __shared__ __align__(16) unsigned char P[16 * 64]; // 16 rows x 32 bf16, swizzled

    bf16x8 qf[4];
    const unsigned short* qrow = qb + ((long)h * S_LEN + q0 + lr) * DH;
    #pragma unroll
    for (int c = 0; c < 4; ++c)
        qf[c] = *(const bf16x8*)(qrow + c * 32 + lg * 8);

    f32x4 o[8] = {};
    float m[4] = {-3e38f, -3e38f, -3e38f, -3e38f};
    float l[4] = {0.f, 0.f, 0.f, 0.f};
    const float scale = 0.08838834764831845f;

    const int nkv = (q0 + 15) / 32 + 1;
    for (int kv = 0; kv < nkv; ++kv) {
        const int kb0 = kv * 32;
        f32x4 sc[2] = {};
        #pragma unroll
        for (int tt = 0; tt < 2; ++tt) {
            const unsigned short* krow = kb + ((long)kh * S_LEN + kb0 + tt * 16 + lr) * DH;
            #pragma unroll
            for (int c = 0; c < 4; ++c) {
                bf16x8 kf = *(const bf16x8*)(krow + c * 32 + lg * 8);
                sc[tt] = __builtin_amdgcn_mfma_f32_16x16x32_bf16(qf[c], kf, sc[tt], 0, 0, 0);
            }
        }
        float p[2][4];
        #pragma unroll
        for (int j = 0; j < 4; ++j) {
            const int qi = q0 + lg * 4 + j;
            float s0 = sc[0][j] * scale;
            float s1 = sc[1][j] * scale;
            if (kb0 + lr > qi)      s0 = -3e38f;
            if (kb0 + 16 + lr > qi) s1 = -3e38f;
            float mx = fmaxf(s0, s1);
            mx = fmaxf(mx, __shfl_xor(mx, 1));
            mx = fmaxf(mx, __shfl_xor(mx, 2));
            mx = fmaxf(mx, __shfl_xor(mx, 4));
            mx = fmaxf(mx, __shfl_xor(mx, 8));
            const float nm  = fmaxf(m[j], mx);
            const float fac = __expf(m[j] - nm);
            const float p0  = __expf(s0 - nm);
            const float p1  = __expf(s1 - nm);
            float rs = p0 + p1;
            rs += __shfl_xor(rs, 1);
            rs += __shfl_xor(rs, 2);
            rs += __shfl_xor(rs, 4);
            rs += __shfl_xor(rs, 8);
            l[j] = l[j] * fac + rs;
            m[j] = nm;
            #pragma unroll
            for (int f = 0; f < 8; ++f) o[f][j] *= fac;
            p[0][j] = p0; p[1][j] = p1;
        }
        #pragma unroll
        for (int tt = 0; tt < 2; ++tt)
            #pragma unroll
            for (int j = 0; j < 4; ++j) {
                const int r  = lg * 4 + j;
                const int cb = (tt * 16 + lr) * 2;
                *(unsigned short*)(P + ((r * 64 + cb) ^ ((r & 3) << 4))) = f2bf(p[tt][j]);
            }
        __syncthreads();
        bf16x8 pa = *(const bf16x8*)(P + ((lr * 64 + lg * 16) ^ ((lr & 3) << 4)));
        #pragma unroll
        for (int f = 0; f < 8; ++f) {
            const unsigned short* vrow =
                vt + ((long)kh * DH + f * 16 + lr) * S_LEN + kb0 + lg * 8;
            bf16x8 vf = *(const bf16x8*)vrow;
            o[f] = __builtin_amdgcn_mfma_f32_16x16x32_bf16(pa, vf, o[f], 0, 0, 0);
        }
        __syncthreads();
    }

    #pragma unroll
    for (int f = 0; f < 8; ++f)
        #pragma unroll
        for (int j = 0; j < 4; ++j) {
            const float ov = o[f][j] / l[j];
            attnb[(long)(q0 + lg * 4 + j) * QD + h * DH + f * 16 + lr] = f2bf(ov);
        }
}

// ---------------- launch ----------------
extern "C" void kernel_launch(void* const* d_in, const int* in_sizes, int n_in,
                              void* d_out, int out_size, void* d_ws, size_t ws_size,
                              hipStream_t stream) {
    const int*   positions = (const int*)d_in[0];
    const float* hidden    = (const float*)d_in[1];
    const float* qkv_w     = (const float*)d_in[2];
    const float* qkv_b     = (const float*)d_in[3];
    const float* qnw       = (const float*)d_in[4];
    const float* knw       = (const float*)d_in[5];
    const float* o_w       = (const float*)d_in[6];
    float* out = (float*)d_out;

    unsigned char* ws = (unsigned char*)d_ws;
    unsigned short* hb    = (unsigned short*)(ws);               // 14,680,064 B
    unsigned short* w1    = (unsigned short*)(ws + 14680064);    // 33,030,144 B
    float*          qkvf  = (float*)(ws + 47710208);             // 37,748,736 B
    unsigned short* qbuf  = (unsigned short*)(ws + 85458944);    // 14,680,064 B
    unsigned short* kbuf  = (unsigned short*)(ws + 100139008);   //  2,097,152 B
    unsigned short* vtb   = (unsigned short*)(ws + 102236160);   //  2,097,152 B (end 104,333,312)
    unsigned short* attnb = (unsigned short*)(ws);               // reuse hb (dead after GEMM1)
    unsigned short* w2    = (unsigned short*)(ws + 14680064);    // reuse w1 (dead after GEMM1)

    cvt_f32_bf16<<<(S_LEN * HIDDEN / 4 + 255) / 256, 256, 0, stream>>>(hidden, hb, S_LEN * HIDDEN / 4);
    cvt_f32_bf16<<<(NQKV * HIDDEN / 4 + 255) / 256, 256, 0, stream>>>(qkv_w, w1, NQKV * HIDDEN / 4);
    gemm_bf16<<<dim3(NQKV / 128, S_LEN / 128), 256, 0, stream>>>(hb, w1, qkvf, qkv_b, S_LEN, NQKV, HIDDEN);
    qkv_post<<<S_LEN, 256, 0, stream>>>(qkvf, positions, qnw, knw, qbuf, kbuf, vtb);
    attn_fwd<<<dim3(S_LEN / 16, NH), 64, 0, stream>>>(qbuf, kbuf, vtb, attnb);
    cvt_f32_bf16<<<(HIDDEN * QD / 4 + 255) / 256, 256, 0, stream>>>(o_w, w2, HIDDEN * QD / 4);
    gemm_bf16<<<dim3(HIDDEN / 128, S_LEN / 128), 256, 0, stream>>>(attnb, w2, out, nullptr, S_LEN, HIDDEN, QD);
}

// Round 2
// 425.558 us; speedup vs baseline: 1.3039x; 1.3039x over previous
//
#include <hip/hip_runtime.h>
#include <hip/hip_bf16.h>
#include <stdint.h>

#define S_LEN 2048
#define HIDDEN 3584
#define NH 28
#define NKH 4
#define DH 128
#define NG 7          // NH / NKH
#define NQKV 4608     // (NH + 2*NKH) * DH
#define QD 3584       // NH*DH
#define KD 512        // NKH*DH

using bf16x8 = __attribute__((ext_vector_type(8))) __bf16;
using f32x4  = __attribute__((ext_vector_type(4))) float;
using f32x16 = __attribute__((ext_vector_type(16))) float;

#define AS3(p) ((__attribute__((address_space(3))) void*)(p))
#define AS1(p) ((const __attribute__((address_space(1))) void*)(p))

__device__ __forceinline__ unsigned short f2bf(float f) {
    unsigned u = __float_as_uint(f);
    u += 0x7FFFu + ((u >> 16) & 1u);
    return (unsigned short)(u >> 16);
}
__device__ __forceinline__ unsigned pkbf(float a, float b) {
    return (unsigned)f2bf(a) | ((unsigned)f2bf(b) << 16);
}

// ---------------- f32 -> bf16 convert (vectorized) ----------------
__global__ void cvt_f32_bf16(const float* __restrict__ in,
                             unsigned short* __restrict__ out, int n4) {
    int i = blockIdx.x * blockDim.x + threadIdx.x;
    if (i >= n4) return;
    float4 v = ((const float4*)in)[i];
    ushort4 o;
    o.x = f2bf(v.x); o.y = f2bf(v.y); o.z = f2bf(v.z); o.w = f2bf(v.w);
    ((ushort4*)out)[i] = o;
}

// ---------------- bf16 GEMM: C[M][N] = A[M][K] * B[N][K]^T (+bias) ----------------
__global__ __launch_bounds__(256) void gemm_bf16(
    const unsigned short* __restrict__ A,
    const unsigned short* __restrict__ B,
    float* __restrict__ C,
    const float* __restrict__ bias,
    int M, int N, int K)
{
    __shared__ __align__(16) unsigned char smem[32768];
    unsigned char* As = smem;           // 128 rows x 128B (64 bf16), swizzled
    unsigned char* Bs = smem + 16384;

    const int tid  = threadIdx.x;
    const int lane = tid & 63;
    const int w    = tid >> 6;
    const int lr   = lane & 15;
    const int lg   = lane >> 4;
    const int m0   = blockIdx.y * 128;
    const int n0   = blockIdx.x * 128;
    const int wm   = (w >> 1) * 64;
    const int wn   = (w & 1) * 64;

    f32x4 acc[4][4] = {};

    const int srow  = lane >> 3;                       // row within chunk
    const int scolb = 16 * ((lane & 7) ^ srow);        // pre-swizzled source col byte

    const int nk = K >> 6;
    for (int kt = 0; kt < nk; ++kt) {
        __syncthreads();
        const long kbyte = (long)kt * 128;
        #pragma unroll
        for (int i = 0; i < 4; ++i) {
            const int c   = w * 4 + i;
            const int row = c * 8 + srow;
            const unsigned char* srcA =
                (const unsigned char*)A + (long)(m0 + row) * (K * 2) + kbyte + scolb;
            __builtin_amdgcn_global_load_lds(AS1(srcA), AS3(As + c * 1024), 16, 0, 0);
            const unsigned char* srcB =
                (const unsigned char*)B + (long)(n0 + row) * (K * 2) + kbyte + scolb;
            __builtin_amdgcn_global_load_lds(AS1(srcB), AS3(Bs + c * 1024), 16, 0, 0);
        }
        __syncthreads();
        #pragma unroll
        for (int kk = 0; kk < 2; ++kk) {
            bf16x8 af[4], bfr[4];
            #pragma unroll
            for (int mi = 0; mi < 4; ++mi) {
                const int row  = wm + mi * 16 + lr;
                const int colb = kk * 64 + lg * 16;
                af[mi] = *(const bf16x8*)(As + row * 128 + (colb ^ ((row & 7) << 4)));
            }
            #pragma unroll
            for (int ni = 0; ni < 4; ++ni) {
                const int row  = wn + ni * 16 + lr;
                const int colb = kk * 64 + lg * 16;
                bfr[ni] = *(const bf16x8*)(Bs + row * 128 + (colb ^ ((row & 7) << 4)));
            }
            #pragma unroll
            for (int mi = 0; mi < 4; ++mi)
                #pragma unroll
                for (int ni = 0; ni < 4; ++ni)
                    acc[mi][ni] = __builtin_amdgcn_mfma_f32_16x16x32_bf16(
                        af[mi], bfr[ni], acc[mi][ni], 0, 0, 0);
        }
    }

    #pragma unroll
    for (int mi = 0; mi < 4; ++mi) {
        #pragma unroll
        for (int ni = 0; ni < 4; ++ni) {
            const int col = n0 + wn + ni * 16 + lr;
            const float bv = bias ? bias[col] : 0.0f;
            #pragma unroll
            for (int j = 0; j < 4; ++j) {
                const int rowg = m0 + wm + mi * 16 + lg * 4 + j;
                C[(long)rowg * N + col] = acc[mi][ni][j] + bv;
            }
        }
    }
}

// ---------------- QKV post: RMSNorm(q,k) + RoPE, layout shuffle ----------------
__global__ __launch_bounds__(256) void qkv_post(
    const float* __restrict__ qkv,       // [S][NQKV]
    const int* __restrict__ positions,
    const float* __restrict__ qnw,       // [QD]
    const float* __restrict__ knw,       // [KD]
    unsigned short* __restrict__ qb,     // [NH][S][DH]
    unsigned short* __restrict__ kb,     // [NKH][S][DH]
    unsigned short* __restrict__ vt)     // [NKH][DH][S]
{
    const int s   = blockIdx.x;
    const int tid = threadIdx.x;
    const float* rowp = qkv + (long)s * NQKV;
    __shared__ float red[256];
    __shared__ float s_rq, s_rk;

    float aq = 0.f;
    for (int i = tid; i < QD; i += 256) { float v = rowp[i]; aq += v * v; }
    red[tid] = aq; __syncthreads();
    for (int off = 128; off > 0; off >>= 1) {
        if (tid < off) red[tid] += red[tid + off];
        __syncthreads();
    }
    if (tid == 0) s_rq = rsqrtf(red[0] / (float)QD + 1e-6f);
    __syncthreads();

    float ak = 0.f;
    for (int i = tid; i < KD; i += 256) { float v = rowp[QD + i]; ak += v * v; }
    red[tid] = ak; __syncthreads();
    for (int off = 128; off > 0; off >>= 1) {
        if (tid < off) red[tid] += red[tid + off];
        __syncthreads();
    }
    if (tid == 0) s_rk = rsqrtf(red[0] / (float)KD + 1e-6f);
    __syncthreads();

    const float rq  = s_rq, rk = s_rk;
    const float pos = (float)positions[s];
    const float c_lnf = 0.21586735253866598f; // ln(1e6)/64

    for (int u = tid; u < NH * 64; u += 256) {
        const int h = u >> 6, j = u & 63;
        const float inv = expf(-(float)j * c_lnf);
        float sn, cs;
        sincosf(pos * inv, &sn, &cs);
        const float x1 = rowp[h * DH + j]      * rq * qnw[h * DH + j];
        const float x2 = rowp[h * DH + 64 + j] * rq * qnw[h * DH + 64 + j];
        qb[((long)h * S_LEN + s) * DH + j]      = f2bf(x1 * cs - x2 * sn);
        qb[((long)h * S_LEN + s) * DH + 64 + j] = f2bf(x2 * cs + x1 * sn);
    }
    for (int u = tid; u < NKH * 64; u += 256) {
        const int h = u >> 6, j = u & 63;
        const float inv = expf(-(float)j * c_lnf);
        float sn, cs;
        sincosf(pos * inv, &sn, &cs);
        const float x1 = rowp[QD + h * DH + j]      * rk * knw[h * DH + j];
        const float x2 = rowp[QD + h * DH + 64 + j] * rk * knw[h * DH + 64 + j];
        kb[((long)h * S_LEN + s) * DH + j]      = f2bf(x1 * cs - x2 * sn);
        kb[((long)h * S_LEN + s) * DH + 64 + j] = f2bf(x2 * cs + x1 * sn);
    }
    for (int u = tid; u < KD; u += 256) {
        const int h = u >> 7, d = u & 127;
        vt[((long)h * DH + d) * S_LEN + s] = f2bf(rowp[QD + KD + u]);
    }
}

// ---------------- flash attention: 1 wave / (head, 32-q-row tile), 32x32 MFMA ----------------
// Swapped operands: scores = mfma(K,Q) and O = mfma(V,P) keep q on the lane axis
// (q = lane&31) for scores, m, l AND O -> softmax is lane-local, no LDS, no barriers.
__global__ __launch_bounds__(64) void attn_fwd(
    const unsigned short* __restrict__ qb,   // [NH][S][DH]
    const unsigned short* __restrict__ kb,   // [NKH][S][DH]
    const unsigned short* __restrict__ vt,   // [NKH][DH][S]
    unsigned short* __restrict__ attnb)      // [S][QD]
{
    const int q0   = S_LEN - 32 - blockIdx.x * 32;   // longest-running blocks first
    const int h    = blockIdx.y;
    const int kh   = h / NG;
    const int lane = threadIdx.x;
    const int lq   = lane & 31;          // q (and d) lane index
    const int hi   = lane >> 5;
    const int hi8  = hi * 8;
    const int hi4  = hi * 4;

    const float scale = 0.08838834764831845f;
    const float RTHR  = 8.0f / 0.08838834764831845f;  // defer-max threshold (raw domain)

    // Q fragments (B-operand): Q[q0+lq][c*16 + hi*8 + e], c = 0..7
    bf16x8 qf[8];
    const unsigned short* qrow = qb + ((long)h * S_LEN + q0 + lq) * DH;
    #pragma unroll
    for (int c = 0; c < 8; ++c)
        qf[c] = *(const bf16x8*)(qrow + c * 16 + hi8);

    f32x16 o[4] = {};
    float m = -3e38f;
    float l = 0.f;

    const int ntiles = q0 / 32 + 1;
    for (int kvt = 0; kvt < ntiles; ++kvt) {
        const int kb0 = kvt * 32;

        // ---- QK^T (swapped): sc[col=q][reg-row=k] ----
        bf16x8 kf[8];
        const unsigned short* krow = kb + ((long)kh * S_LEN + kb0 + lq) * DH;
        #pragma unroll
        for (int c = 0; c < 8; ++c)
            kf[c] = *(const bf16x8*)(krow + c * 16 + hi8);
        f32x16 sc = {};
        #pragma unroll
        for (int c = 0; c < 8; ++c)
            sc = __builtin_amdgcn_mfma_f32_32x32x16_bf16(kf[c], qf[c], sc, 0, 0, 0);

        // ---- mask (diagonal tile only) ----
        float s[16];
        if (kvt == ntiles - 1) {
            #pragma unroll
            for (int r = 0; r < 16; ++r) {
                const int kr = (r & 3) + 8 * (r >> 2) + hi4;
                s[r] = (kr > lq) ? -3e38f : sc[r];
            }
        } else {
            #pragma unroll
            for (int r = 0; r < 16; ++r) s[r] = sc[r];
        }

        // ---- online softmax, lane-local ----
        float mx = s[0];
        #pragma unroll
        for (int r = 1; r < 16; ++r) mx = fmaxf(mx, s[r]);
        mx = fmaxf(mx, __shfl_xor(mx, 32));

        if (!__all(mx <= m + RTHR)) {
            const float nm  = fmaxf(m, mx);
            const float fac = __expf((m - nm) * scale);
            l *= fac;
            #pragma unroll
            for (int d0 = 0; d0 < 4; ++d0)
                #pragma unroll
                for (int r = 0; r < 16; ++r) o[d0][r] *= fac;
            m = nm;
        }

        float p[16];
        float ps = 0.f;
        #pragma unroll
        for (int r = 0; r < 16; ++r) {
            p[r] = __expf((s[r] - m) * scale);
            ps += p[r];
        }
        ps += __shfl_xor(ps, 32);
        l += ps;

        // ---- P (f32, k in regs) -> PV B-fragments (k on ctr axis) ----
        // pack pairs to bf16 dwords, exchange halves via shfl_xor(32)
        unsigned pa01 = pkbf(p[0],  p[1]),  pa23 = pkbf(p[2],  p[3]);
        unsigned pb01 = pkbf(p[4],  p[5]),  pb23 = pkbf(p[6],  p[7]);
        unsigned pc01 = pkbf(p[8],  p[9]),  pc23 = pkbf(p[10], p[11]);
        unsigned pd01 = pkbf(p[12], p[13]), pd23 = pkbf(p[14], p[15]);
        unsigned xa01 = __shfl_xor((int)pa01, 32), xa23 = __shfl_xor((int)pa23, 32);
        unsigned xb01 = __shfl_xor((int)pb01, 32), xb23 = __shfl_xor((int)pb23, 32);
        unsigned xc01 = __shfl_xor((int)pc01, 32), xc23 = __shfl_xor((int)pc23, 32);
        unsigned xd01 = __shfl_xor((int)pd01, 32), xd23 = __shfl_xor((int)pd23, 32);

        union { unsigned u[4]; bf16x8 v; } pf0, pf1;
        pf0.u[0] = hi ? xb01 : pa01;
        pf0.u[1] = hi ? xb23 : pa23;
        pf0.u[2] = hi ? pb01 : xa01;
        pf0.u[3] = hi ? pb23 : xa23;
        pf1.u[0] = hi ? xd01 : pc01;
        pf1.u[1] = hi ? xd23 : pc23;
        pf1.u[2] = hi ? pd01 : xc01;
        pf1.u[3] = hi ? pd23 : xc23;

        // ---- PV (swapped): o[col=q][reg-row=d] ----
        #pragma unroll
        for (int d0 = 0; d0 < 4; ++d0) {
            const unsigned short* vrow =
                vt + ((long)kh * DH + d0 * 32 + lq) * S_LEN + kb0 + hi8;
            bf16x8 vf0 = *(const bf16x8*)vrow;
            bf16x8 vf1 = *(const bf16x8*)(vrow + 16);
            o[d0] = __builtin_amdgcn_mfma_f32_32x32x16_bf16(vf0, pf0.v, o[d0], 0, 0, 0);
            o[d0] = __builtin_amdgcn_mfma_f32_32x32x16_bf16(vf1, pf1.v, o[d0], 0, 0, 0);
        }
    }

    // ---- epilogue: out[q0+lq][h*DH + d], d = d0*32 + 8g + hi4 + 0..3 ----
    const float rl = 1.0f / l;
    unsigned short* orow = attnb + (long)(q0 + lq) * QD + h * DH;
    #pragma unroll
    for (int d0 = 0; d0 < 4; ++d0) {
        #pragma unroll
        for (int g = 0; g < 4; ++g) {
            ushort4 s4;
            s4.x = f2bf(o[d0][4 * g + 0] * rl);
            s4.y = f2bf(o[d0][4 * g + 1] * rl);
            s4.z = f2bf(o[d0][4 * g + 2] * rl);
            s4.w = f2bf(o[d0][4 * g + 3] * rl);
            *(ushort4*)(orow + d0 * 32 + 8 * g + hi4) = s4;
        }
    }
}

// ---------------- launch ----------------
extern "C" void kernel_launch(void* const* d_in, const int* in_sizes, int n_in,
                              void* d_out, int out_size, void* d_ws, size_t ws_size,
                              hipStream_t stream) {
    const int*   positions = (const int*)d_in[0];
    const float* hidden    = (const float*)d_in[1];
    const float* qkv_w     = (const float*)d_in[2];
    const float* qkv_b     = (const float*)d_in[3];
    const float* qnw       = (const float*)d_in[4];
    const float* knw       = (const float*)d_in[5];
    const float* o_w       = (const float*)d_in[6];
    float* out = (float*)d_out;

    unsigned char* ws = (unsigned char*)d_ws;
    unsigned short* hb    = (unsigned short*)(ws);               // 14,680,064 B
    unsigned short* w1    = (unsigned short*)(ws + 14680064);    // 33,030,144 B
    float*          qkvf  = (float*)(ws + 47710208);             // 37,748,736 B
    unsigned short* qbuf  = (unsigned short*)(ws + 85458944);    // 14,680,064 B
    unsigned short* kbuf  = (unsigned short*)(ws + 100139008);   //  2,097,152 B
    unsigned short* vtb   = (unsigned short*)(ws + 102236160);   //  2,097,152 B
    unsigned short* attnb = (unsigned short*)(ws);               // reuse hb
    unsigned short* w2    = (unsigned short*)(ws + 14680064);    // reuse w1

    cvt_f32_bf16<<<(S_LEN * HIDDEN / 4 + 255) / 256, 256, 0, stream>>>(hidden, hb, S_LEN * HIDDEN / 4);
    cvt_f32_bf16<<<(NQKV * HIDDEN / 4 + 255) / 256, 256, 0, stream>>>(qkv_w, w1, NQKV * HIDDEN / 4);
    gemm_bf16<<<dim3(NQKV / 128, S_LEN / 128), 256, 0, stream>>>(hb, w1, qkvf, qkv_b, S_LEN, NQKV, HIDDEN);
    qkv_post<<<S_LEN, 256, 0, stream>>>(qkvf, positions, qnw, knw, qbuf, kbuf, vtb);
    attn_fwd<<<dim3(S_LEN / 32, NH), 64, 0, stream>>>(qbuf, kbuf, vtb, attnb);
    cvt_f32_bf16<<<(HIDDEN * QD / 4 + 255) / 256, 256, 0, stream>>>(o_w, w2, HIDDEN * QD / 4);
    gemm_bf16<<<dim3(HIDDEN / 128, S_LEN / 128), 256, 0, stream>>>(attnb, w2, out, nullptr, S_LEN, HIDDEN, QD);
}